// Round 4
// baseline (724.549 us; speedup 1.0000x reference)
//
#include <hip/hip_runtime.h>
#include <math.h>

#define NN 10000
#define EE 160000
#define ET 170000
#define FIN 256
#define HH 8
#define HC 512
#define NCLS 40
#define ELLW 96
#define REPS 8     // DIAGNOSTIC: internal repetition to surface per-phase counters

typedef _Float16 f16;
using f16x8 = __attribute__((ext_vector_type(8))) _Float16;
using f16x4 = __attribute__((ext_vector_type(4))) _Float16;
using f32x4 = __attribute__((ext_vector_type(4))) float;

#define MFMA16(a, b, c) __builtin_amdgcn_mfma_f32_16x16x32_f16((a), (b), (c), 0, 0, 0)

// ---------- prep: x fp32->f16 cast + weight transposes + cnt zero ----------
__global__ __launch_bounds__(256) void prep_kernel(const float* __restrict__ x,
                                                   const float* __restrict__ W0,
                                                   const float* __restrict__ W1,
                                                   const float* __restrict__ W2,
                                                   f16* __restrict__ xh,
                                                   f16* __restrict__ w0T,
                                                   f16* __restrict__ w1T,
                                                   f16* __restrict__ w2T,
                                                   int* __restrict__ cnt) {
    int i = blockIdx.x * 256 + threadIdx.x;
    for (int rep = 0; rep < REPS; ++rep) {
        if (i < NN) cnt[i] = 0;
        if (i < NN * FIN / 4) {
            float4 v = ((const float4*)x)[i];
            f16x4 o;
            o[0] = (f16)v.x; o[1] = (f16)v.y; o[2] = (f16)v.z; o[3] = (f16)v.w;
            ((f16x4*)xh)[i] = o;
        } else {
            int j = i - NN * FIN / 4;
            if (j < HC * FIN) {
                int n = j >> 8, k = j & 255;
                w0T[j] = (f16)W0[(size_t)k * HC + n];
            } else if (j < HC * FIN + HC * HC) {
                int q = j - HC * FIN;
                int n = q >> 9, k = q & 511;
                w1T[q] = (f16)W1[(size_t)k * HC + n];
            } else if (j < HC * FIN + HC * HC + NCLS * HC) {
                int q = j - HC * FIN - HC * HC;
                int n = q >> 9, k = q & 511;
                w2T[q] = (f16)W2[(size_t)k * NCLS + n];
            }
        }
        asm volatile("" ::: "memory");
    }
}

__global__ __launch_bounds__(256) void scatter_ell(const int* __restrict__ ei,
                                                   int* __restrict__ cnt,
                                                   int* __restrict__ ell) {
    int e = blockIdx.x * 256 + threadIdx.x;
    if (e >= ET) return;
    int s, d;
    if (e < EE) { s = ei[e]; d = ei[EE + e]; }
    else        { s = e - EE; d = s; }          // self-loops appended
    int pos = atomicAdd(&cnt[d], 1);
    if (pos < ELLW) ell[(size_t)d * ELLW + pos] = s;
}

// ---------- GEMM + fused attn: B-resident LDS, barrier-free K-loop ----------
template <int K>
__global__ __launch_bounds__(512) void gemm_attn(const f16* __restrict__ A,
                                                 const f16* __restrict__ BT,
                                                 const float* __restrict__ a_src,
                                                 const float* __restrict__ a_dst,
                                                 f16* __restrict__ hx2,
                                                 float* __restrict__ al_s,
                                                 float* __restrict__ al_d) {
    constexpr int KK = K / 32;            // MFMA K-steps (16 or 8)
    constexpr int CH = K / 8;             // 16B chunks per B row (64 or 32)
    __shared__ f16 Bs[64 * K];            // 64 KB (K=512) / 32 KB (K=256)
    int t = threadIdx.x;
    int hp = blockIdx.x;                  // head pair
    int lane = t & 63, w = t >> 6;
    int fm = lane & 15, g = lane >> 4;
    int bm = blockIdx.y * 128 + w * 16;
    int row = bm + fm;
    bool rok = row < NN;

    f16x8 af[KK];
#pragma unroll
    for (int kk = 0; kk < KK; ++kk) {
        uint4 r = rok ? *(const uint4*)(A + (size_t)row * K + kk * 32 + g * 8)
                      : make_uint4(0u, 0u, 0u, 0u);
        af[kk] = __builtin_bit_cast(f16x8, r);
    }

    for (int rep = 0; rep < REPS; ++rep) {
        for (int sl = 0; sl < 2; ++sl) {
            int h = hp * 2 + sl;
            const f16* bsrc = BT + (size_t)h * 64 * K;
            for (int c = t; c < 64 * CH; c += 512) {
                int brow = c / CH;
                int j = c - brow * CH;
                uint4 v = *(const uint4*)(bsrc + (size_t)brow * K + j * 8);
                *(uint4*)&Bs[(size_t)brow * K + ((j ^ (brow & 7)) * 8)] = v;
            }
            __syncthreads();

            f32x4 acc[4] = {};
#pragma unroll
            for (int kk = 0; kk < KK; ++kk) {
#pragma unroll
                for (int nt = 0; nt < 4; ++nt) {
                    f16x8 b = *(const f16x8*)
                        &Bs[(nt * 16 + fm) * K + (((kk * 4 + g) ^ (fm & 7)) * 8)];
                    acc[nt] = MFMA16(af[kk], b, acc[nt]);
                }
            }

            float asc[4], adc[4];
#pragma unroll
            for (int nt = 0; nt < 4; ++nt) {
                asc[nt] = a_src[h * 64 + nt * 16 + fm];
                adc[nt] = a_dst[h * 64 + nt * 16 + fm];
            }
#pragma unroll
            for (int r = 0; r < 4; ++r) {
                int orow = bm + g * 4 + r;          // C/D: row=(lane>>4)*4+reg
                float s = acc[0][r] * asc[0] + acc[1][r] * asc[1] +
                          acc[2][r] * asc[2] + acc[3][r] * asc[3];
                float d = acc[0][r] * adc[0] + acc[1][r] * adc[1] +
                          acc[2][r] * adc[2] + acc[3][r] * adc[3];
#pragma unroll
                for (int off = 1; off < 16; off <<= 1) {
                    s += __shfl_xor(s, off);
                    d += __shfl_xor(d, off);
                }
                if (orow < NN) {
                    if (fm == 0) {
                        al_s[orow * 8 + h] = s;
                        al_d[orow * 8 + h] = d;
                    }
#pragma unroll
                    for (int nt = 0; nt < 4; ++nt)
                        hx2[(size_t)orow * HC + h * 64 + nt * 16 + fm] =
                            (f16)acc[nt][r];
                }
            }
            __syncthreads();
        }
        asm volatile("" ::: "memory");
    }
}

// ---------- layer 2: barrier-free B-resident GEMM 512->40 + fused attn ------
__global__ __launch_bounds__(256) void gemm2_attn(const f16* __restrict__ A,
                                                  const f16* __restrict__ BT,
                                                  const float* __restrict__ a_src2,
                                                  const float* __restrict__ a_dst2,
                                                  float* __restrict__ hx40,
                                                  float* __restrict__ als2,
                                                  float* __restrict__ ald2) {
    __shared__ f16 Bs[48 * HC];    // 48 KB, rows 40..47 zero
    int t = threadIdx.x;
    int lane = t & 63, w = t >> 6;
    int fm = lane & 15, g = lane >> 4;
    int bm = blockIdx.x * 64 + w * 16;
    int row = bm + fm;
    bool rok = row < NN;

    f16x8 af[16];
#pragma unroll
    for (int kk = 0; kk < 16; ++kk) {
        uint4 r = rok ? *(const uint4*)(A + (size_t)row * HC + kk * 32 + g * 8)
                      : make_uint4(0u, 0u, 0u, 0u);
        af[kk] = __builtin_bit_cast(f16x8, r);
    }

    for (int rep = 0; rep < REPS; ++rep) {
        for (int c = t; c < 48 * 64; c += 256) {
            int brow = c >> 6, j = c & 63;
            uint4 v = make_uint4(0u, 0u, 0u, 0u);
            if (brow < NCLS) v = *(const uint4*)(BT + (size_t)brow * HC + j * 8);
            *(uint4*)&Bs[brow * HC + ((j ^ (brow & 7)) * 8)] = v;
        }
        __syncthreads();

        f32x4 acc[3] = {};
#pragma unroll
        for (int kk = 0; kk < 16; ++kk) {
#pragma unroll
            for (int nt = 0; nt < 3; ++nt) {
                f16x8 b = *(const f16x8*)
                    &Bs[(nt * 16 + fm) * HC + (((kk * 4 + g) ^ (fm & 7)) * 8)];
                acc[nt] = MFMA16(af[kk], b, acc[nt]);
            }
        }

        float a2s[3], a2d[3];
#pragma unroll
        for (int nt = 0; nt < 3; ++nt) {
            int col = nt * 16 + fm;
            a2s[nt] = (col < NCLS) ? a_src2[col] : 0.f;
            a2d[nt] = (col < NCLS) ? a_dst2[col] : 0.f;
        }
#pragma unroll
        for (int r = 0; r < 4; ++r) {
            int orow = bm + g * 4 + r;
            float s = acc[0][r] * a2s[0] + acc[1][r] * a2s[1] + acc[2][r] * a2s[2];
            float d = acc[0][r] * a2d[0] + acc[1][r] * a2d[1] + acc[2][r] * a2d[2];
#pragma unroll
            for (int off = 1; off < 16; off <<= 1) {
                s += __shfl_xor(s, off);
                d += __shfl_xor(d, off);
            }
            if (orow < NN) {
                if (fm == 0) { als2[orow] = s; ald2[orow] = d; }
#pragma unroll
                for (int nt = 0; nt < 3; ++nt) {
                    int col = nt * 16 + fm;
                    if (col < NCLS) hx40[(size_t)orow * NCLS + col] = acc[nt][r];
                }
            }
        }
        __syncthreads();               // WAR on Bs before next rep
        asm volatile("" ::: "memory");
    }
}

// ---------- aggregate: 2 waves/node, quad-granular edge split ----------
__global__ __launch_bounds__(256) void agg_ell(const f16* __restrict__ hx2,
                                               const float* __restrict__ al_s,
                                               const float* __restrict__ al_d,
                                               const int* __restrict__ cnt,
                                               const int* __restrict__ ell,
                                               const float* __restrict__ bias,
                                               f16* __restrict__ outF) {
    __shared__ float accbuf[2][64][8];
    __shared__ float denbuf[2][64];
    int t = threadIdx.x;
    int lane = t & 63, w = t >> 6;
    int p = w >> 1, sub = w & 1;
    int n = blockIdx.x * 2 + p;
    bool nok = n < NN;
    int ch = lane * 8;
    int h = lane >> 3;
    for (int rep = 0; rep < REPS; ++rep) {
        float acc[8] = {0.f, 0.f, 0.f, 0.f, 0.f, 0.f, 0.f, 0.f};
        float den = 0.f;
        if (nok) {
            float ald = al_d[n * HH + h];
            int dg = cnt[n]; if (dg > ELLW) dg = ELLW;
            const int* ep = ell + (size_t)n * ELLW;
            int nq = dg >> 2;
            for (int q = sub; q < nq; q += 2) {
                int4 ss = *(const int4*)(ep + (q << 2));
                float e0 = al_s[ss.x * HH + h], e1 = al_s[ss.y * HH + h];
                float e2 = al_s[ss.z * HH + h], e3 = al_s[ss.w * HH + h];
                uint4 v0 = *(const uint4*)(hx2 + (size_t)ss.x * HC + ch);
                uint4 v1 = *(const uint4*)(hx2 + (size_t)ss.y * HC + ch);
                uint4 v2 = *(const uint4*)(hx2 + (size_t)ss.z * HC + ch);
                uint4 v3 = *(const uint4*)(hx2 + (size_t)ss.w * HC + ch);
                e0 += ald; e0 = e0 > 0.f ? e0 : 0.2f * e0;
                e1 += ald; e1 = e1 > 0.f ? e1 : 0.2f * e1;
                e2 += ald; e2 = e2 > 0.f ? e2 : 0.2f * e2;
                e3 += ald; e3 = e3 > 0.f ? e3 : 0.2f * e3;
                float w0 = __expf(e0), w1 = __expf(e1);
                float w2 = __expf(e2), w3 = __expf(e3);
                f16x8 f0 = __builtin_bit_cast(f16x8, v0);
                f16x8 f1 = __builtin_bit_cast(f16x8, v1);
                f16x8 f2 = __builtin_bit_cast(f16x8, v2);
                f16x8 f3 = __builtin_bit_cast(f16x8, v3);
#pragma unroll
                for (int j = 0; j < 8; ++j)
                    acc[j] += w0 * (float)f0[j] + w1 * (float)f1[j] +
                              w2 * (float)f2[j] + w3 * (float)f3[j];
                den += w0 + w1 + w2 + w3;
            }
            if (sub == (nq & 1)) {                  // tail to lighter wave
                for (int i2 = nq << 2; i2 < dg; ++i2) {
                    int s = ep[i2];
                    float e = al_s[s * HH + h] + ald;
                    e = e > 0.f ? e : 0.2f * e;
                    float wgt = __expf(e);
                    uint4 v = *(const uint4*)(hx2 + (size_t)s * HC + ch);
                    f16x8 f = __builtin_bit_cast(f16x8, v);
#pragma unroll
                    for (int j = 0; j < 8; ++j) acc[j] += wgt * (float)f[j];
                    den += wgt;
                }
            }
        }
        if (sub == 1) {
#pragma unroll
            for (int j = 0; j < 8; ++j) accbuf[p][lane][j] = acc[j];
            denbuf[p][lane] = den;
        }
        __syncthreads();
        if (sub == 0 && nok) {
#pragma unroll
            for (int j = 0; j < 8; ++j) acc[j] += accbuf[p][lane][j];
            den += denbuf[p][lane];
            float inv = 1.f / (den + 1e-16f);
            float4 b0v = *(const float4*)(bias + ch);
            float4 b1v = *(const float4*)(bias + ch + 4);
            float bb[8] = {b0v.x, b0v.y, b0v.z, b0v.w, b1v.x, b1v.y, b1v.z, b1v.w};
            f16x8 o;
#pragma unroll
            for (int j = 0; j < 8; ++j) {
                float v = acc[j] * inv + bb[j];
                v = v > 0.f ? v : expm1f(v);    // ELU
                o[j] = (f16)v;
            }
            *(uint4*)(outF + (size_t)n * HC + ch) = __builtin_bit_cast(uint4, o);
        }
        __syncthreads();                        // WAR on accbuf before next rep
        asm volatile("" ::: "memory");
    }
}

// ---------- final aggregate (H=1, C=40), fp32, no ELU ----------
__global__ __launch_bounds__(64) void agg2_final(const float* __restrict__ hx40,
                                                 const float* __restrict__ als,
                                                 const float* __restrict__ aldp,
                                                 const int* __restrict__ cnt,
                                                 const int* __restrict__ ell,
                                                 const float* __restrict__ b2,
                                                 float* __restrict__ out) {
    int n = blockIdx.x;
    int c = threadIdx.x;
    for (int rep = 0; rep < REPS; ++rep) {
        float ald = aldp[n];
        int dg = cnt[n]; if (dg > ELLW) dg = ELLW;
        const int* ep = ell + (size_t)n * ELLW;
        float acc = 0.f, den = 0.f;
        int i = 0;
        for (; i + 4 <= dg; i += 4) {
            int4 ss = *(const int4*)(ep + i);
            float e0 = als[ss.x], e1 = als[ss.y], e2 = als[ss.z], e3 = als[ss.w];
            float v0 = 0.f, v1 = 0.f, v2 = 0.f, v3 = 0.f;
            if (c < NCLS) {
                v0 = hx40[(size_t)ss.x * NCLS + c];
                v1 = hx40[(size_t)ss.y * NCLS + c];
                v2 = hx40[(size_t)ss.z * NCLS + c];
                v3 = hx40[(size_t)ss.w * NCLS + c];
            }
            e0 += ald; e0 = e0 > 0.f ? e0 : 0.2f * e0;
            e1 += ald; e1 = e1 > 0.f ? e1 : 0.2f * e1;
            e2 += ald; e2 = e2 > 0.f ? e2 : 0.2f * e2;
            e3 += ald; e3 = e3 > 0.f ? e3 : 0.2f * e3;
            float w0 = __expf(e0), w1 = __expf(e1), w2 = __expf(e2), w3 = __expf(e3);
            acc += w0 * v0 + w1 * v1 + w2 * v2 + w3 * v3;
            den += w0 + w1 + w2 + w3;
        }
        for (; i < dg; ++i) {
            int s = ep[i];
            float e = als[s] + ald;
            e = e > 0.f ? e : 0.2f * e;
            float wgt = __expf(e);
            if (c < NCLS) acc += wgt * hx40[(size_t)s * NCLS + c];
            den += wgt;
        }
        if (c < NCLS) out[(size_t)n * NCLS + c] = acc / (den + 1e-16f) + b2[c];
        asm volatile("" ::: "memory");
    }
}

extern "C" void kernel_launch(void* const* d_in, const int* in_sizes, int n_in,
                              void* d_out, int out_size, void* d_ws, size_t ws_size,
                              hipStream_t stream) {
    const float* x   = (const float*)d_in[0];
    const int*   ei  = (const int*)  d_in[1];
    const float* W0  = (const float*)d_in[2];
    const float* as0 = (const float*)d_in[3];
    const float* ad0 = (const float*)d_in[4];
    const float* b0  = (const float*)d_in[5];
    const float* W1  = (const float*)d_in[6];
    const float* as1 = (const float*)d_in[7];
    const float* ad1 = (const float*)d_in[8];
    const float* b1  = (const float*)d_in[9];
    const float* W2  = (const float*)d_in[10];
    const float* as2 = (const float*)d_in[11];
    const float* ad2 = (const float*)d_in[12];
    const float* b2  = (const float*)d_in[13];
    float* out = (float*)d_out;

    char* p = (char*)d_ws;
    int* cnt  = (int*)p; p += 40064;
    int* ell  = (int*)p; p += (size_t)NN * ELLW * 4;    // 3.84 MB
    f16* w0T  = (f16*)p; p += HC * FIN * 2;
    f16* w1T  = (f16*)p; p += HC * HC * 2;
    f16* w2T  = (f16*)p; p += NCLS * HC * 2;
    f16* xh   = (f16*)p; p += (size_t)NN * FIN * 2;     // 5.12 MB f16 x
    f16* hxA  = (f16*)p; p += (size_t)NN * HC * 2;
    f16* hxB  = (f16*)p; p += (size_t)NN * HC * 2;
    f16* fA   = (f16*)p; p += (size_t)NN * HC * 2;
    f16* fB   = (f16*)p; p += (size_t)NN * HC * 2;
    float* hx40 = (float*)p; p += (size_t)NN * NCLS * 4;
    float* als0 = (float*)p; p += NN * HH * 4;
    float* ald0 = (float*)p; p += NN * HH * 4;
    float* als1 = (float*)p; p += NN * HH * 4;
    float* ald1 = (float*)p; p += NN * HH * 4;
    float* als2 = (float*)p; p += NN * 4;
    float* ald2 = (float*)p; p += NN * 4;

    const int NBR = (NN + 127) / 128;   // 79 row-chunks (layers 0/1)
    const int NAG = (NN + 1) / 2;       // 5000 blocks (2 waves/node agg)
    const int NB2 = (NN + 63) / 64;     // 157 row-blocks (layer 2)
    const int PREP = NN * FIN / 4 + HC * FIN + HC * HC + NCLS * HC;  // 1053696

    prep_kernel<<<(PREP + 255) / 256, 256, 0, stream>>>(
        x, W0, W1, W2, xh, w0T, w1T, w2T, cnt);
    scatter_ell<<<(ET + 255) / 256, 256, 0, stream>>>(ei, cnt, ell);

    dim3 gA(4, NBR);   // 4 head-pairs x 79 row-chunks = 316 blocks
    // layer 0
    gemm_attn<FIN><<<gA, 512, 0, stream>>>(xh, w0T, as0, ad0, hxA, als0, ald0);
    agg_ell<<<NAG, 256, 0, stream>>>(hxA, als0, ald0, cnt, ell, b0, fA);
    // layer 1
    gemm_attn<HC><<<gA, 512, 0, stream>>>(fA, w1T, as1, ad1, hxB, als1, ald1);
    agg_ell<<<NAG, 256, 0, stream>>>(hxB, als1, ald1, cnt, ell, b1, fB);
    // layer 2
    gemm2_attn<<<NB2, 256, 0, stream>>>(fB, w2T, as2, ad2, hx40, als2, ald2);
    agg2_final<<<NN, 64, 0, stream>>>(hx40, als2, ald2, cnt, ell, b2, out);
}

// Round 5
// 199.322 us; speedup vs baseline: 3.6351x; 3.6351x over previous
//
#include <hip/hip_runtime.h>
#include <math.h>

#define NN 10000
#define EE 160000
#define ET 170000
#define FIN 256
#define HH 8
#define HC 512
#define NCLS 40
#define ELLW 96

typedef _Float16 f16;
using f16x8 = __attribute__((ext_vector_type(8))) _Float16;
using f32x4 = __attribute__((ext_vector_type(4))) float;

#define MFMA16(a, b, c) __builtin_amdgcn_mfma_f32_16x16x32_f16((a), (b), (c), 0, 0, 0)

// f32 acc += f16(lo/hi of packed) * f32 w  -- forced mixed-precision FMA
__device__ __forceinline__ void fmamix2(float& alo, float& ahi, unsigned pk, float w) {
    asm("v_fma_mix_f32 %0, %1, %2, %0 op_sel:[0,0,0] op_sel_hi:[1,0,0]"
        : "+v"(alo) : "v"(pk), "v"(w));
    asm("v_fma_mix_f32 %0, %1, %2, %0 op_sel:[1,0,0] op_sel_hi:[1,0,0]"
        : "+v"(ahi) : "v"(pk), "v"(w));
}

// ---------- prep0: cnt zero + W0 transpose (tiny) ----------
__global__ __launch_bounds__(256) void prep0(const float* __restrict__ W0,
                                             f16* __restrict__ w0T,
                                             int* __restrict__ cnt) {
    int i = blockIdx.x * 256 + threadIdx.x;
    if (i < NN) cnt[i] = 0;
    if (i < HC * FIN) {
        int n = i >> 8, k = i & 255;
        w0T[i] = (f16)W0[(size_t)k * HC + n];
    }
}

// ---------- mega0: gemmL0 (fp32 A) + scatter + W1/W2 transpose ----------
// blocks [0,316): gemm L0 (hp = b%4, chunk = b/4), 512 thr
// blocks [316,649): scatter_ell
// blocks [649,1161): W1 transpose; [1161,1201): W2 transpose
__global__ __launch_bounds__(512) void mega0(const float* __restrict__ x,
                                             const f16* __restrict__ w0T,
                                             const float* __restrict__ a_src,
                                             const float* __restrict__ a_dst,
                                             const int* __restrict__ ei,
                                             const float* __restrict__ W1,
                                             const float* __restrict__ W2,
                                             f16* __restrict__ hx2,
                                             float* __restrict__ al_s,
                                             float* __restrict__ al_d,
                                             int* __restrict__ cnt,
                                             int* __restrict__ ell,
                                             f16* __restrict__ w1T,
                                             f16* __restrict__ w2T) {
    __shared__ f16 Bs[64 * FIN];          // 32 KB
    int b = blockIdx.x;
    int t = threadIdx.x;
    if (b >= 316) {
        if (b < 649) {                    // scatter
            int e = (b - 316) * 512 + t;
            if (e < ET) {
                int s, d;
                if (e < EE) { s = ei[e]; d = ei[EE + e]; }
                else        { s = e - EE; d = s; }
                int pos = atomicAdd(&cnt[d], 1);
                if (pos < ELLW) ell[(size_t)d * ELLW + pos] = s;
            }
        } else if (b < 1161) {            // W1 transpose
            int j = (b - 649) * 512 + t;  // < 262144 always
            int n = j >> 9, k = j & 511;
            w1T[j] = (f16)W1[(size_t)k * HC + n];
        } else {                          // W2 transpose
            int j = (b - 1161) * 512 + t;
            if (j < NCLS * HC) {
                int n = j >> 9, k = j & 511;
                w2T[j] = (f16)W2[(size_t)k * NCLS + n];
            }
        }
        return;
    }
    // ---- gemm L0: fp32 A rows -> f16 frags, B-resident LDS ----
    int hp = b & 3, chunk = b >> 2;
    int lane = t & 63, w = t >> 6;
    int fm = lane & 15, g = lane >> 4;
    int bm = chunk * 128 + w * 16;
    int row = bm + fm;
    bool rok = row < NN;

    f16x8 af[8];
#pragma unroll
    for (int kk = 0; kk < 8; ++kk) {
        float4 lo = make_float4(0.f, 0.f, 0.f, 0.f), hi = lo;
        if (rok) {
            const float* ap = x + (size_t)row * FIN + kk * 32 + g * 8;
            lo = *(const float4*)ap;
            hi = *(const float4*)(ap + 4);
        }
        f16x8 v;
        v[0] = (f16)lo.x; v[1] = (f16)lo.y; v[2] = (f16)lo.z; v[3] = (f16)lo.w;
        v[4] = (f16)hi.x; v[5] = (f16)hi.y; v[6] = (f16)hi.z; v[7] = (f16)hi.w;
        af[kk] = v;
    }

    for (int sl = 0; sl < 2; ++sl) {
        int h = hp * 2 + sl;
        const f16* bsrc = w0T + (size_t)h * 64 * FIN;
        for (int c = t; c < 64 * 32; c += 512) {
            int brow = c >> 5, j = c & 31;
            uint4 v = *(const uint4*)(bsrc + (size_t)brow * FIN + j * 8);
            *(uint4*)&Bs[(size_t)brow * FIN + ((j ^ (brow & 7)) * 8)] = v;
        }
        __syncthreads();

        f32x4 acc[4] = {};
#pragma unroll
        for (int kk = 0; kk < 8; ++kk) {
#pragma unroll
            for (int nt = 0; nt < 4; ++nt) {
                f16x8 bb = *(const f16x8*)
                    &Bs[(nt * 16 + fm) * FIN + (((kk * 4 + g) ^ (fm & 7)) * 8)];
                acc[nt] = MFMA16(af[kk], bb, acc[nt]);
            }
        }

        float asc[4], adc[4];
#pragma unroll
        for (int nt = 0; nt < 4; ++nt) {
            asc[nt] = a_src[h * 64 + nt * 16 + fm];
            adc[nt] = a_dst[h * 64 + nt * 16 + fm];
        }
#pragma unroll
        for (int r = 0; r < 4; ++r) {
            int orow = bm + g * 4 + r;          // C/D: row=(lane>>4)*4+reg
            float s = acc[0][r] * asc[0] + acc[1][r] * asc[1] +
                      acc[2][r] * asc[2] + acc[3][r] * asc[3];
            float d = acc[0][r] * adc[0] + acc[1][r] * adc[1] +
                      acc[2][r] * adc[2] + acc[3][r] * adc[3];
#pragma unroll
            for (int off = 1; off < 16; off <<= 1) {
                s += __shfl_xor(s, off);
                d += __shfl_xor(d, off);
            }
            if (orow < NN) {
                if (fm == 0) {
                    al_s[orow * 8 + h] = s;
                    al_d[orow * 8 + h] = d;
                }
#pragma unroll
                for (int nt = 0; nt < 4; ++nt)
                    hx2[(size_t)orow * HC + h * 64 + nt * 16 + fm] =
                        (f16)acc[nt][r];
            }
        }
        __syncthreads();
    }
}

// ---------- GEMM + fused attn (f16 A), layer 1 ----------
template <int K>
__global__ __launch_bounds__(512) void gemm_attn(const f16* __restrict__ A,
                                                 const f16* __restrict__ BT,
                                                 const float* __restrict__ a_src,
                                                 const float* __restrict__ a_dst,
                                                 f16* __restrict__ hx2,
                                                 float* __restrict__ al_s,
                                                 float* __restrict__ al_d) {
    constexpr int KK = K / 32;
    constexpr int CH = K / 8;
    __shared__ f16 Bs[64 * K];
    int t = threadIdx.x;
    int hp = blockIdx.x;
    int lane = t & 63, w = t >> 6;
    int fm = lane & 15, g = lane >> 4;
    int bm = blockIdx.y * 128 + w * 16;
    int row = bm + fm;
    bool rok = row < NN;

    f16x8 af[KK];
#pragma unroll
    for (int kk = 0; kk < KK; ++kk) {
        uint4 r = rok ? *(const uint4*)(A + (size_t)row * K + kk * 32 + g * 8)
                      : make_uint4(0u, 0u, 0u, 0u);
        af[kk] = __builtin_bit_cast(f16x8, r);
    }

    for (int sl = 0; sl < 2; ++sl) {
        int h = hp * 2 + sl;
        const f16* bsrc = BT + (size_t)h * 64 * K;
        for (int c = t; c < 64 * CH; c += 512) {
            int brow = c / CH;
            int j = c - brow * CH;
            uint4 v = *(const uint4*)(bsrc + (size_t)brow * K + j * 8);
            *(uint4*)&Bs[(size_t)brow * K + ((j ^ (brow & 7)) * 8)] = v;
        }
        __syncthreads();

        f32x4 acc[4] = {};
#pragma unroll
        for (int kk = 0; kk < KK; ++kk) {
#pragma unroll
            for (int nt = 0; nt < 4; ++nt) {
                f16x8 b = *(const f16x8*)
                    &Bs[(nt * 16 + fm) * K + (((kk * 4 + g) ^ (fm & 7)) * 8)];
                acc[nt] = MFMA16(af[kk], b, acc[nt]);
            }
        }

        float asc[4], adc[4];
#pragma unroll
        for (int nt = 0; nt < 4; ++nt) {
            asc[nt] = a_src[h * 64 + nt * 16 + fm];
            adc[nt] = a_dst[h * 64 + nt * 16 + fm];
        }
#pragma unroll
        for (int r = 0; r < 4; ++r) {
            int orow = bm + g * 4 + r;
            float s = acc[0][r] * asc[0] + acc[1][r] * asc[1] +
                      acc[2][r] * asc[2] + acc[3][r] * asc[3];
            float d = acc[0][r] * adc[0] + acc[1][r] * adc[1] +
                      acc[2][r] * adc[2] + acc[3][r] * adc[3];
#pragma unroll
            for (int off = 1; off < 16; off <<= 1) {
                s += __shfl_xor(s, off);
                d += __shfl_xor(d, off);
            }
            if (orow < NN) {
                if (fm == 0) {
                    al_s[orow * 8 + h] = s;
                    al_d[orow * 8 + h] = d;
                }
#pragma unroll
                for (int nt = 0; nt < 4; ++nt)
                    hx2[(size_t)orow * HC + h * 64 + nt * 16 + fm] =
                        (f16)acc[nt][r];
            }
        }
        __syncthreads();
    }
}

// ---------- layer 2: barrier-free B-resident GEMM 512->40 + fused attn ------
__global__ __launch_bounds__(256) void gemm2_attn(const f16* __restrict__ A,
                                                  const f16* __restrict__ BT,
                                                  const float* __restrict__ a_src2,
                                                  const float* __restrict__ a_dst2,
                                                  float* __restrict__ hx40,
                                                  float* __restrict__ als2,
                                                  float* __restrict__ ald2) {
    __shared__ f16 Bs[48 * HC];
    int t = threadIdx.x;
    int lane = t & 63, w = t >> 6;
    int fm = lane & 15, g = lane >> 4;
    int bm = blockIdx.x * 64 + w * 16;
    int row = bm + fm;
    bool rok = row < NN;

    for (int c = t; c < 48 * 64; c += 256) {
        int brow = c >> 6, j = c & 63;
        uint4 v = make_uint4(0u, 0u, 0u, 0u);
        if (brow < NCLS) v = *(const uint4*)(BT + (size_t)brow * HC + j * 8);
        *(uint4*)&Bs[brow * HC + ((j ^ (brow & 7)) * 8)] = v;
    }

    f16x8 af[16];
#pragma unroll
    for (int kk = 0; kk < 16; ++kk) {
        uint4 r = rok ? *(const uint4*)(A + (size_t)row * HC + kk * 32 + g * 8)
                      : make_uint4(0u, 0u, 0u, 0u);
        af[kk] = __builtin_bit_cast(f16x8, r);
    }
    __syncthreads();

    f32x4 acc[3] = {};
#pragma unroll
    for (int kk = 0; kk < 16; ++kk) {
#pragma unroll
        for (int nt = 0; nt < 3; ++nt) {
            f16x8 b = *(const f16x8*)
                &Bs[(nt * 16 + fm) * HC + (((kk * 4 + g) ^ (fm & 7)) * 8)];
            acc[nt] = MFMA16(af[kk], b, acc[nt]);
        }
    }

    float a2s[3], a2d[3];
#pragma unroll
    for (int nt = 0; nt < 3; ++nt) {
        int col = nt * 16 + fm;
        a2s[nt] = (col < NCLS) ? a_src2[col] : 0.f;
        a2d[nt] = (col < NCLS) ? a_dst2[col] : 0.f;
    }
#pragma unroll
    for (int r = 0; r < 4; ++r) {
        int orow = bm + g * 4 + r;
        float s = acc[0][r] * a2s[0] + acc[1][r] * a2s[1] + acc[2][r] * a2s[2];
        float d = acc[0][r] * a2d[0] + acc[1][r] * a2d[1] + acc[2][r] * a2d[2];
#pragma unroll
        for (int off = 1; off < 16; off <<= 1) {
            s += __shfl_xor(s, off);
            d += __shfl_xor(d, off);
        }
        if (orow < NN) {
            if (fm == 0) { als2[orow] = s; ald2[orow] = d; }
#pragma unroll
            for (int nt = 0; nt < 3; ++nt) {
                int col = nt * 16 + fm;
                if (col < NCLS) hx40[(size_t)orow * NCLS + col] = acc[nt][r];
            }
        }
    }
}

// ---------- aggregate: 2 waves/node, quad split, v_fma_mix accumulate ----------
__global__ __launch_bounds__(256) void agg_ell(const f16* __restrict__ hx2,
                                               const float* __restrict__ al_s,
                                               const float* __restrict__ al_d,
                                               const int* __restrict__ cnt,
                                               const int* __restrict__ ell,
                                               const float* __restrict__ bias,
                                               f16* __restrict__ outF) {
    __shared__ float accbuf[2][64][8];
    __shared__ float denbuf[2][64];
    int t = threadIdx.x;
    int lane = t & 63, w = t >> 6;
    int p = w >> 1, sub = w & 1;
    int n = blockIdx.x * 2 + p;
    bool nok = n < NN;
    int ch = lane * 8;
    int h = lane >> 3;
    float acc[8] = {0.f, 0.f, 0.f, 0.f, 0.f, 0.f, 0.f, 0.f};
    float den = 0.f;
    if (nok) {
        float ald = al_d[n * HH + h];
        int dg = cnt[n]; if (dg > ELLW) dg = ELLW;
        const int* ep = ell + (size_t)n * ELLW;
        int nq = dg >> 2;
        for (int q = sub; q < nq; q += 2) {
            int4 ss = *(const int4*)(ep + (q << 2));
            float e0 = al_s[ss.x * HH + h], e1 = al_s[ss.y * HH + h];
            float e2 = al_s[ss.z * HH + h], e3 = al_s[ss.w * HH + h];
            uint4 v0 = *(const uint4*)(hx2 + (size_t)ss.x * HC + ch);
            uint4 v1 = *(const uint4*)(hx2 + (size_t)ss.y * HC + ch);
            uint4 v2 = *(const uint4*)(hx2 + (size_t)ss.z * HC + ch);
            uint4 v3 = *(const uint4*)(hx2 + (size_t)ss.w * HC + ch);
            e0 += ald; e0 = e0 > 0.f ? e0 : 0.2f * e0;
            e1 += ald; e1 = e1 > 0.f ? e1 : 0.2f * e1;
            e2 += ald; e2 = e2 > 0.f ? e2 : 0.2f * e2;
            e3 += ald; e3 = e3 > 0.f ? e3 : 0.2f * e3;
            float w0 = __expf(e0), w1 = __expf(e1);
            float w2 = __expf(e2), w3 = __expf(e3);
            unsigned q0[4] = {v0.x, v0.y, v0.z, v0.w};
            unsigned q1[4] = {v1.x, v1.y, v1.z, v1.w};
            unsigned q2[4] = {v2.x, v2.y, v2.z, v2.w};
            unsigned q3[4] = {v3.x, v3.y, v3.z, v3.w};
#pragma unroll
            for (int j = 0; j < 4; ++j) {
                fmamix2(acc[2 * j], acc[2 * j + 1], q0[j], w0);
                fmamix2(acc[2 * j], acc[2 * j + 1], q1[j], w1);
                fmamix2(acc[2 * j], acc[2 * j + 1], q2[j], w2);
                fmamix2(acc[2 * j], acc[2 * j + 1], q3[j], w3);
            }
            den += w0 + w1 + w2 + w3;
        }
        if (sub == (nq & 1)) {                  // tail to lighter wave
            for (int i2 = nq << 2; i2 < dg; ++i2) {
                int s = ep[i2];
                float e = al_s[s * HH + h] + ald;
                e = e > 0.f ? e : 0.2f * e;
                float wgt = __expf(e);
                uint4 v = *(const uint4*)(hx2 + (size_t)s * HC + ch);
                unsigned qq[4] = {v.x, v.y, v.z, v.w};
#pragma unroll
                for (int j = 0; j < 4; ++j)
                    fmamix2(acc[2 * j], acc[2 * j + 1], qq[j], wgt);
                den += wgt;
            }
        }
    }
    if (sub == 1) {
#pragma unroll
        for (int j = 0; j < 8; ++j) accbuf[p][lane][j] = acc[j];
        denbuf[p][lane] = den;
    }
    __syncthreads();
    if (sub == 0 && nok) {
#pragma unroll
        for (int j = 0; j < 8; ++j) acc[j] += accbuf[p][lane][j];
        den += denbuf[p][lane];
        float inv = 1.f / (den + 1e-16f);
        float4 b0v = *(const float4*)(bias + ch);
        float4 b1v = *(const float4*)(bias + ch + 4);
        float bb[8] = {b0v.x, b0v.y, b0v.z, b0v.w, b1v.x, b1v.y, b1v.z, b1v.w};
        f16x8 o;
#pragma unroll
        for (int j = 0; j < 8; ++j) {
            float v = acc[j] * inv + bb[j];
            v = v > 0.f ? v : expm1f(v);        // ELU
            o[j] = (f16)v;
        }
        *(uint4*)(outF + (size_t)n * HC + ch) = __builtin_bit_cast(uint4, o);
    }
}

// ---------- final aggregate (H=1, C=40), 4 waves/block ----------
__global__ __launch_bounds__(256) void agg2_final(const float* __restrict__ hx40,
                                                  const float* __restrict__ als,
                                                  const float* __restrict__ aldp,
                                                  const int* __restrict__ cnt,
                                                  const int* __restrict__ ell,
                                                  const float* __restrict__ b2,
                                                  float* __restrict__ out) {
    int t = threadIdx.x;
    int n = blockIdx.x * 4 + (t >> 6);
    int c = t & 63;
    if (n >= NN) return;
    float ald = aldp[n];
    int dg = cnt[n]; if (dg > ELLW) dg = ELLW;
    const int* ep = ell + (size_t)n * ELLW;
    float acc = 0.f, den = 0.f;
    int i = 0;
    for (; i + 4 <= dg; i += 4) {
        int4 ss = *(const int4*)(ep + i);
        float e0 = als[ss.x], e1 = als[ss.y], e2 = als[ss.z], e3 = als[ss.w];
        float v0 = 0.f, v1 = 0.f, v2 = 0.f, v3 = 0.f;
        if (c < NCLS) {
            v0 = hx40[(size_t)ss.x * NCLS + c];
            v1 = hx40[(size_t)ss.y * NCLS + c];
            v2 = hx40[(size_t)ss.z * NCLS + c];
            v3 = hx40[(size_t)ss.w * NCLS + c];
        }
        e0 += ald; e0 = e0 > 0.f ? e0 : 0.2f * e0;
        e1 += ald; e1 = e1 > 0.f ? e1 : 0.2f * e1;
        e2 += ald; e2 = e2 > 0.f ? e2 : 0.2f * e2;
        e3 += ald; e3 = e3 > 0.f ? e3 : 0.2f * e3;
        float w0 = __expf(e0), w1 = __expf(e1), w2 = __expf(e2), w3 = __expf(e3);
        acc += w0 * v0 + w1 * v1 + w2 * v2 + w3 * v3;
        den += w0 + w1 + w2 + w3;
    }
    for (; i < dg; ++i) {
        int s = ep[i];
        float e = als[s] + ald;
        e = e > 0.f ? e : 0.2f * e;
        float wgt = __expf(e);
        if (c < NCLS) acc += wgt * hx40[(size_t)s * NCLS + c];
        den += wgt;
    }
    if (c < NCLS) out[(size_t)n * NCLS + c] = acc / (den + 1e-16f) + b2[c];
}

extern "C" void kernel_launch(void* const* d_in, const int* in_sizes, int n_in,
                              void* d_out, int out_size, void* d_ws, size_t ws_size,
                              hipStream_t stream) {
    const float* x   = (const float*)d_in[0];
    const int*   ei  = (const int*)  d_in[1];
    const float* W0  = (const float*)d_in[2];
    const float* as0 = (const float*)d_in[3];
    const float* ad0 = (const float*)d_in[4];
    const float* b0  = (const float*)d_in[5];
    const float* W1  = (const float*)d_in[6];
    const float* as1 = (const float*)d_in[7];
    const float* ad1 = (const float*)d_in[8];
    const float* b1  = (const float*)d_in[9];
    const float* W2  = (const float*)d_in[10];
    const float* as2 = (const float*)d_in[11];
    const float* ad2 = (const float*)d_in[12];
    const float* b2  = (const float*)d_in[13];
    float* out = (float*)d_out;

    char* p = (char*)d_ws;
    int* cnt  = (int*)p; p += 40064;
    int* ell  = (int*)p; p += (size_t)NN * ELLW * 4;    // 3.84 MB
    f16* w0T  = (f16*)p; p += HC * FIN * 2;
    f16* w1T  = (f16*)p; p += HC * HC * 2;
    f16* w2T  = (f16*)p; p += NCLS * HC * 2;
    f16* hxA  = (f16*)p; p += (size_t)NN * HC * 2;
    f16* hxB  = (f16*)p; p += (size_t)NN * HC * 2;
    f16* fA   = (f16*)p; p += (size_t)NN * HC * 2;
    f16* fB   = (f16*)p; p += (size_t)NN * HC * 2;
    float* hx40 = (float*)p; p += (size_t)NN * NCLS * 4;
    float* als0 = (float*)p; p += NN * HH * 4;
    float* ald0 = (float*)p; p += NN * HH * 4;
    float* als1 = (float*)p; p += NN * HH * 4;
    float* ald1 = (float*)p; p += NN * HH * 4;
    float* als2 = (float*)p; p += NN * 4;
    float* ald2 = (float*)p; p += NN * 4;

    const int NBR = (NN + 127) / 128;   // 79 row-chunks (layer 1)
    const int NAG = (NN + 1) / 2;       // 5000 blocks (agg)
    const int NB2 = (NN + 63) / 64;     // 157 row-blocks (layer 2)

    // 1) tiny prep: cnt zero + W0 transpose
    prep0<<<(HC * FIN + 255) / 256, 256, 0, stream>>>(W0, w0T, cnt);
    // 2) mega0: gemm L0 (316) + scatter (333) + W1 (512) + W2 (40) = 1201 blocks
    mega0<<<1201, 512, 0, stream>>>(x, w0T, as0, ad0, ei, W1, W2,
                                    hxA, als0, ald0, cnt, ell, w1T, w2T);
    // 3) agg layer 0
    agg_ell<<<NAG, 256, 0, stream>>>(hxA, als0, ald0, cnt, ell, b0, fA);
    // 4) gemm layer 1
    dim3 gA(4, NBR);
    gemm_attn<HC><<<gA, 512, 0, stream>>>(fA, w1T, as1, ad1, hxB, als1, ald1);
    // 5) agg layer 1
    agg_ell<<<NAG, 256, 0, stream>>>(hxB, als1, ald1, cnt, ell, b1, fB);
    // 6) gemm layer 2
    gemm2_attn<<<NB2, 256, 0, stream>>>(fB, w2T, as2, ad2, hx40, als2, ald2);
    // 7) final aggregate
    agg2_final<<<(NN + 3) / 4, 256, 0, stream>>>(hx40, als2, ald2, cnt, ell, b2, out);
}